// Round 5
// baseline (239.102 us; speedup 1.0000x reference)
//
#include <hip/hip_runtime.h>

typedef __bf16 bf16x8 __attribute__((ext_vector_type(8)));
typedef float f32x4 __attribute__((ext_vector_type(4)));
typedef unsigned int u32x4 __attribute__((ext_vector_type(4)));
typedef unsigned int u32x2 __attribute__((ext_vector_type(2)));
typedef u32x4 u32x4a __attribute__((may_alias));
typedef u32x2 u32x2a __attribute__((may_alias));
typedef f32x4 f32x4a __attribute__((may_alias));
typedef unsigned int u32a __attribute__((may_alias));

#define NITER 2  // 512-thread block => 8 waves * 32 pts * 2 = 512 pts/block; grid = n/512

__device__ inline unsigned short f2b(float f) {  // f32 -> bf16 RNE (prep only)
    unsigned int x;
    __builtin_memcpy(&x, &f, 4);
    unsigned int r = (x + 0x7FFFu + ((x >> 16) & 1u)) >> 16;
    return (unsigned short)r;
}
__device__ inline unsigned int cvt_pk_bf16(float lo, float hi) {
    unsigned int r;
    asm("v_cvt_pk_bf16_f32 %0, %1, %2" : "=v"(r) : "v"(lo), "v"(hi));
    return r;
}
__device__ inline float vexp2(float x) { float r; asm("v_exp_f32 %0, %1" : "=v"(r) : "v"(x)); return r; }
__device__ inline float vlog2(float x) { float r; asm("v_log_f32 %0, %1" : "=v"(r) : "v"(x)); return r; }
__device__ inline float vrcp(float x)  { float r; asm("v_rcp_f32 %0, %1" : "=v"(r) : "v"(x)); return r; }
// softplus(x) = ln2 * log2(1 + 2^(x*log2e)) — f32-safe for |x|<80
__device__ inline float softplus_f(float x) {
    return 0.69314718f * vlog2(1.f + vexp2(1.44269504f * x));
}
__device__ inline float sigmoid_f(float x) {
    return vrcp(1.f + vexp2(-1.44269504f * x));
}
__device__ inline bf16x8 as_bf16x8(u32x4 v) { return __builtin_bit_cast(bf16x8, v); }

// softplus + pack to 2 u32 (4 bf16), stays in registers
__device__ inline u32x2 sp_pk(f32x4 acc) {
    u32x2 r = {cvt_pk_bf16(softplus_f(acc[0]), softplus_f(acc[1])),
               cvt_pk_bf16(softplus_f(acc[2]), softplus_f(acc[3]))};
    return r;
}

// In-register layer redistribution (replaces the s_h LDS round-trip).
// Output layout: lane (q=l>>4,c=l&15) holds outs nt*16+q*4+{0..3} as pk[nt] (2 u32).
// Next-layer B-frag: lane (q,c) needs outs [8q..8q+7] = 4 u32 words, sourced from
// partner lanes 2(q&1)*16+c (idx0) and (2(q&1)+1)*16+c (idx1), register pair
// (lo=nt_even, hi=nt_odd) selected by q>=2. Verified vs old hw[] semantics.
__device__ inline u32x4 gather8(u32x2 lo, u32x2 hi, int idx0, int idx1, bool hisel) {
    int a0 = __builtin_amdgcn_ds_bpermute(idx0, (int)lo[0]);
    int b0 = __builtin_amdgcn_ds_bpermute(idx0, (int)hi[0]);
    int a1 = __builtin_amdgcn_ds_bpermute(idx0, (int)lo[1]);
    int b1 = __builtin_amdgcn_ds_bpermute(idx0, (int)hi[1]);
    int a2 = __builtin_amdgcn_ds_bpermute(idx1, (int)lo[0]);
    int b2 = __builtin_amdgcn_ds_bpermute(idx1, (int)hi[0]);
    int a3 = __builtin_amdgcn_ds_bpermute(idx1, (int)lo[1]);
    int b3 = __builtin_amdgcn_ds_bpermute(idx1, (int)hi[1]);
    u32x4 r = {(unsigned)(hisel ? b0 : a0), (unsigned)(hisel ? b1 : a1),
               (unsigned)(hisel ? b2 : a2), (unsigned)(hisel ? b3 : a3)};
    return r;
}
// feat gather: 16 raw occ2 outs (2 words/lane); q>=2 lanes get don't-care values
// (their rgb0 feat weight rows are zero) — matches old stale-read behavior.
__device__ inline u32x4 gather4(u32x2 a, int idx0, int idx1) {
    u32x4 r = {(unsigned)__builtin_amdgcn_ds_bpermute(idx0, (int)a[0]),
               (unsigned)__builtin_amdgcn_ds_bpermute(idx0, (int)a[1]),
               (unsigned)__builtin_amdgcn_ds_bpermute(idx1, (int)a[0]),
               (unsigned)__builtin_amdgcn_ds_bpermute(idx1, (int)a[1])};
    return r;
}

// ws layout: [0..287] f32 biases | byte 1152: ushort frag-major weights 36*64*8
// bias map: [0]ob0 [64]ob1 [128]ob2 [144]rb1 [208]rb2(pad->16) [224]rgb_b0'(folded latent)
// frag bases: occ0:0(Nt4,Kt1) occ1:4(4,2) occ2:12(1,2) rgb0:14(4,3) rgb1:26(4,2) rgb2:34(1,2)
// frag: lane l holds W[k=kt*32+(l>>4)*8+j][n=nt*16+(l&15)]
// rgb0 x-row map: k<32 emb, 32..58 dir(rows 32..58), 59..63 zero,
//                 64..95 feat tile: k-local kl=1..15 -> W row 58+kl, kl=0 & kl>=16 -> ZERO

__global__ __launch_bounds__(256) void prep_weights(
    const float* __restrict__ oW0, const float* __restrict__ ob0,
    const float* __restrict__ oW1, const float* __restrict__ ob1,
    const float* __restrict__ oW2, const float* __restrict__ ob2,
    const float* __restrict__ rW0, const float* __restrict__ rb0,
    const float* __restrict__ rW1, const float* __restrict__ rb1,
    const float* __restrict__ rW2, const float* __restrict__ rb2,
    const float* __restrict__ rlat, const int* __restrict__ lidx,
    float* __restrict__ wsf, ushort* __restrict__ wsw)
{
    const int bid = blockIdx.x, tid = threadIdx.x;
    __shared__ float red[256];

    if (bid == 0) {  // plain biases
        for (int i = tid; i < 224; i += 256) {
            float v;
            if (i < 64)       v = ob0[i];
            else if (i < 128) v = ob1[i - 64];
            else if (i < 144) v = ob2[i - 128];
            else if (i < 208) v = rb1[i - 144];
            else              v = (i - 208 < 3) ? rb2[i - 208] : 0.f;
            wsf[i] = v;
        }
    }
    if (bid == 7) {  // parallel latent fold: rgb_b0' = rgb_b0 + latent @ rgb_W0[74:202]
        const int outn = tid & 63, sl = tid >> 6;  // 4 slices x 32 k
        const float* lat = rlat + (size_t)lidx[0] * 128;
        float p = 0.f;
        for (int k = sl * 32; k < sl * 32 + 32; k++)
            p = fmaf(lat[k], rW0[(74 + k) * 64 + outn], p);
        red[tid] = p;
        __syncthreads();
        if (tid < 64)
            wsf[224 + tid] = rb0[tid] + red[tid] + red[64 + tid] + red[128 + tid] + red[192 + tid];
    }
    // fragment-major weight table: 2304 frag-lanes split across 8 blocks
    for (int t = tid; t < 288; t += 256) {
        const int s = bid * 288 + t;
        const int frag = s >> 6, lane = s & 63;
        const int qq = lane >> 4, cc = lane & 15;
        const float* W;
        int ldn = 64, nt = 0, kt = 0;
        bool isr0 = false, isr2 = false;
        if (frag < 4)       { W = oW0; nt = frag; kt = 0; }
        else if (frag < 12) { W = oW1; int f = frag - 4;  nt = f >> 1; kt = f & 1; }
        else if (frag < 14) { W = oW2; ldn = 16; nt = 0; kt = frag - 12; }
        else if (frag < 26) { W = rW0; int f = frag - 14; nt = f / 3; kt = f - nt * 3; isr0 = true; }
        else if (frag < 34) { W = rW1; int f = frag - 26; nt = f >> 1; kt = f & 1; }
        else                { W = rW2; ldn = 3; nt = 0; kt = frag - 34; isr2 = true; }
        const int nn = nt * 16 + cc;
        __align__(16) ushort vals[8];
#pragma unroll
        for (int j = 0; j < 8; j++) {
            int k = kt * 32 + qq * 8 + j;
            float v = 0.f;
            if (isr0) {
                int ks = -1;
                if (k < 59) ks = k;                            // emb + dir rows
                else if (k >= 65 && k < 80) ks = k - 65 + 59;  // feat kl=1..15 -> rows 59..73
                if (ks >= 0) v = W[ks * 64 + nn];
            } else if (isr2) {
                if (nn < 3) v = W[k * 3 + nn];
            } else {
                v = W[k * ldn + nn];
            }
            vals[j] = f2b(v);
        }
        *(u32x4a*)&wsw[s * 8] = *(const u32x4a*)vals;
    }
}

// Transposed-compute kernel: D = W^T_tile · X^T_tile (row=out, col=point).
// R5: s_h ELIMINATED — layer redistribution via ds_bpermute (in-wave, no LDS
// capacity, no write->read latency chain). LDS = 36864(s_w)+1152(s_b) = 38,016 B
// -> 4 blocks/CU; grid doubled (NITER 2) -> target 24-32 waves/CU (was 16).
// R4 counters: LDS 42% + VALU 44% + MFMA 10% = 96% serialized; this buys overlap.
__global__ __launch_bounds__(512, 7) void net_mfma(
    const float* __restrict__ emb, const float* __restrict__ dir,
    const float* __restrict__ wsf, const ushort* __restrict__ wsw,
    float* __restrict__ out, int n)
{
    __shared__ __align__(16) ushort s_w[36 * 64 * 8];    // 36,864 B
    __shared__ __align__(16) float s_b[288];             //  1,152 B  biases (f32)

    const int tid = threadIdx.x;
    for (int i = tid; i < 36 * 64; i += 512)
        *(u32x4a*)&s_w[i * 8] = *(const u32x4a*)(wsw + i * 8);
    for (int i = tid; i < 288; i += 512) s_b[i] = wsf[i];
    __syncthreads();

    const int wave = tid >> 6, lane = tid & 63, q = lane >> 4, c = lane & 15;
    const int q4 = q * 4, q8 = q * 8;
    const bool hisel = q >= 2;
    // bpermute byte indices: partner lanes 2(q&1)*16+c and +16
    const int idx0 = ((((lane >> 4) & 1) << 5) | c) << 2;
    const int idx1 = idx0 | 64;
    const long dlim = (long)n * 27;

    for (int it = 0; it < NITER; ++it) {
        const ushort* sw = s_w;       // opaque per-iter bases: block LICM of the
        const float*  sb = s_b;       // weight-frag + bias LDS loads
        asm volatile("" : "+v"(sw), "+v"(sb));

        const long p0 = (long)blockIdx.x * 512 + it * 256 + wave * 32;  // A: +c, B: +16+c

        // ---- input B-fragments straight from global (both groups) ----
        bf16x8 x_embA, x_embB, x_dirA, x_dirB;
        {
            const float* ep = emb + (p0 + c) * 32 + q8;
            f32x4 e0 = *(const f32x4a*)ep;
            f32x4 e1 = *(const f32x4a*)(ep + 4);
            u32x4 pk = {cvt_pk_bf16(e0[0], e0[1]), cvt_pk_bf16(e0[2], e0[3]),
                        cvt_pk_bf16(e1[0], e1[1]), cvt_pk_bf16(e1[2], e1[3])};
            x_embA = as_bf16x8(pk);
            const float* ep2 = emb + (p0 + 16 + c) * 32 + q8;
            f32x4 f0 = *(const f32x4a*)ep2;
            f32x4 f1 = *(const f32x4a*)(ep2 + 4);
            u32x4 pk2 = {cvt_pk_bf16(f0[0], f0[1]), cvt_pk_bf16(f0[2], f0[3]),
                         cvt_pk_bf16(f1[0], f1[1]), cvt_pk_bf16(f1[2], f1[3])};
            x_embB = as_bf16x8(pk2);
        }
        {
            // k-local >= 27 lanes carry garbage; rgb0 dir weight rows 27..31 are zero
            const long ibA = (p0 + c) * 27 + q8;
            f32x4 d0, d1;
            if (ibA + 8 <= dlim) {
                d0 = *(const f32x4a*)(dir + ibA);
                d1 = *(const f32x4a*)(dir + ibA + 4);
            } else {
#pragma unroll
                for (int j = 0; j < 4; j++) d0[j] = (ibA + j < dlim) ? dir[ibA + j] : 0.f;
#pragma unroll
                for (int j = 0; j < 4; j++) d1[j] = (ibA + 4 + j < dlim) ? dir[ibA + 4 + j] : 0.f;
            }
            u32x4 pk = {cvt_pk_bf16(d0[0], d0[1]), cvt_pk_bf16(d0[2], d0[3]),
                        cvt_pk_bf16(d1[0], d1[1]), cvt_pk_bf16(d1[2], d1[3])};
            x_dirA = as_bf16x8(pk);
            const long ibB = (p0 + 16 + c) * 27 + q8;
            f32x4 g0, g1;
            if (ibB + 8 <= dlim) {
                g0 = *(const f32x4a*)(dir + ibB);
                g1 = *(const f32x4a*)(dir + ibB + 4);
            } else {
#pragma unroll
                for (int j = 0; j < 4; j++) g0[j] = (ibB + j < dlim) ? dir[ibB + j] : 0.f;
#pragma unroll
                for (int j = 0; j < 4; j++) g1[j] = (ibB + 4 + j < dlim) ? dir[ibB + 4 + j] : 0.f;
            }
            u32x4 pk2 = {cvt_pk_bf16(g0[0], g0[1]), cvt_pk_bf16(g0[2], g0[3]),
                         cvt_pk_bf16(g1[0], g1[1]), cvt_pk_bf16(g1[2], g1[3])};
            x_dirB = as_bf16x8(pk2);
        }

        u32x2 pkA[4], pkB[4];

        // ---- occ layer 0: K=32 (emb), out 64 ----
#pragma unroll
        for (int nt = 0; nt < 4; ++nt) {
            bf16x8 w = as_bf16x8(*(const u32x4a*)&sw[((0 + nt) * 64 + lane) * 8]);
            f32x4 b = *(const f32x4a*)&sb[0 + nt * 16 + q4];
            f32x4 aA = __builtin_amdgcn_mfma_f32_16x16x32_bf16(w, x_embA, b, 0, 0, 0);
            f32x4 aB = __builtin_amdgcn_mfma_f32_16x16x32_bf16(w, x_embB, b, 0, 0, 0);
            pkA[nt] = sp_pk(aA);
            pkB[nt] = sp_pk(aB);
        }
        bf16x8 hA0 = as_bf16x8(gather8(pkA[0], pkA[1], idx0, idx1, hisel));
        bf16x8 hA1 = as_bf16x8(gather8(pkA[2], pkA[3], idx0, idx1, hisel));
        bf16x8 hB0 = as_bf16x8(gather8(pkB[0], pkB[1], idx0, idx1, hisel));
        bf16x8 hB1 = as_bf16x8(gather8(pkB[2], pkB[3], idx0, idx1, hisel));

        // ---- occ layer 1: K=64, out 64 ----
#pragma unroll
        for (int nt = 0; nt < 4; ++nt) {
            bf16x8 w0 = as_bf16x8(*(const u32x4a*)&sw[((4 + nt * 2 + 0) * 64 + lane) * 8]);
            bf16x8 w1 = as_bf16x8(*(const u32x4a*)&sw[((4 + nt * 2 + 1) * 64 + lane) * 8]);
            f32x4 b = *(const f32x4a*)&sb[64 + nt * 16 + q4];
            f32x4 aA = __builtin_amdgcn_mfma_f32_16x16x32_bf16(w0, hA0, b, 0, 0, 0);
            aA = __builtin_amdgcn_mfma_f32_16x16x32_bf16(w1, hA1, aA, 0, 0, 0);
            f32x4 aB = __builtin_amdgcn_mfma_f32_16x16x32_bf16(w0, hB0, b, 0, 0, 0);
            aB = __builtin_amdgcn_mfma_f32_16x16x32_bf16(w1, hB1, aB, 0, 0, 0);
            pkA[nt] = sp_pk(aA);
            pkB[nt] = sp_pk(aB);
        }
        bf16x8 gA0 = as_bf16x8(gather8(pkA[0], pkA[1], idx0, idx1, hisel));
        bf16x8 gA1 = as_bf16x8(gather8(pkA[2], pkA[3], idx0, idx1, hisel));
        bf16x8 gB0 = as_bf16x8(gather8(pkB[0], pkB[1], idx0, idx1, hisel));
        bf16x8 gB1 = as_bf16x8(gather8(pkB[2], pkB[3], idx0, idx1, hisel));

        // ---- occ layer 2: K=64, out 16 (raw -> feat; occ = sigmoid(out0)) ----
        float occA, occB;
        bf16x8 xfA, xfB;
        {
            bf16x8 w0 = as_bf16x8(*(const u32x4a*)&sw[(12 * 64 + lane) * 8]);
            bf16x8 w1 = as_bf16x8(*(const u32x4a*)&sw[(13 * 64 + lane) * 8]);
            f32x4 b = *(const f32x4a*)&sb[128 + q4];
            f32x4 aA = __builtin_amdgcn_mfma_f32_16x16x32_bf16(w0, gA0, b, 0, 0, 0);
            aA = __builtin_amdgcn_mfma_f32_16x16x32_bf16(w1, gA1, aA, 0, 0, 0);
            f32x4 aB = __builtin_amdgcn_mfma_f32_16x16x32_bf16(w0, gB0, b, 0, 0, 0);
            aB = __builtin_amdgcn_mfma_f32_16x16x32_bf16(w1, gB1, aB, 0, 0, 0);
            occA = sigmoid_f(aA[0]);  // 1-exp(-softplus(h)) == sigmoid(h); valid on q==0
            occB = sigmoid_f(aB[0]);
            u32x2 p2A = {cvt_pk_bf16(aA[0], aA[1]), cvt_pk_bf16(aA[2], aA[3])};
            u32x2 p2B = {cvt_pk_bf16(aB[0], aB[1]), cvt_pk_bf16(aB[2], aB[3])};
            xfA = as_bf16x8(gather4(p2A, idx0, idx1));  // raw outs 0..15 (out0 nulled
            xfB = as_bf16x8(gather4(p2B, idx0, idx1));  //  by zero weight row)
        }
        // ---- rgb layer 0: K=96 (emb|dir|feat), out 64, bias = folded rgb_b0' ----
#pragma unroll
        for (int nt = 0; nt < 4; ++nt) {
            bf16x8 w0 = as_bf16x8(*(const u32x4a*)&sw[((14 + nt * 3 + 0) * 64 + lane) * 8]);
            bf16x8 w1 = as_bf16x8(*(const u32x4a*)&sw[((14 + nt * 3 + 1) * 64 + lane) * 8]);
            bf16x8 w2 = as_bf16x8(*(const u32x4a*)&sw[((14 + nt * 3 + 2) * 64 + lane) * 8]);
            f32x4 b = *(const f32x4a*)&sb[224 + nt * 16 + q4];
            f32x4 aA = __builtin_amdgcn_mfma_f32_16x16x32_bf16(w0, x_embA, b, 0, 0, 0);
            aA = __builtin_amdgcn_mfma_f32_16x16x32_bf16(w1, x_dirA, aA, 0, 0, 0);
            aA = __builtin_amdgcn_mfma_f32_16x16x32_bf16(w2, xfA, aA, 0, 0, 0);
            f32x4 aB = __builtin_amdgcn_mfma_f32_16x16x32_bf16(w0, x_embB, b, 0, 0, 0);
            aB = __builtin_amdgcn_mfma_f32_16x16x32_bf16(w1, x_dirB, aB, 0, 0, 0);
            aB = __builtin_amdgcn_mfma_f32_16x16x32_bf16(w2, xfB, aB, 0, 0, 0);
            pkA[nt] = sp_pk(aA);
            pkB[nt] = sp_pk(aB);
        }
        bf16x8 rA0 = as_bf16x8(gather8(pkA[0], pkA[1], idx0, idx1, hisel));
        bf16x8 rA1 = as_bf16x8(gather8(pkA[2], pkA[3], idx0, idx1, hisel));
        bf16x8 rB0 = as_bf16x8(gather8(pkB[0], pkB[1], idx0, idx1, hisel));
        bf16x8 rB1 = as_bf16x8(gather8(pkB[2], pkB[3], idx0, idx1, hisel));

        // ---- rgb layer 1: K=64, out 64 ----
#pragma unroll
        for (int nt = 0; nt < 4; ++nt) {
            bf16x8 w0 = as_bf16x8(*(const u32x4a*)&sw[((26 + nt * 2 + 0) * 64 + lane) * 8]);
            bf16x8 w1 = as_bf16x8(*(const u32x4a*)&sw[((26 + nt * 2 + 1) * 64 + lane) * 8]);
            f32x4 b = *(const f32x4a*)&sb[144 + nt * 16 + q4];
            f32x4 aA = __builtin_amdgcn_mfma_f32_16x16x32_bf16(w0, rA0, b, 0, 0, 0);
            aA = __builtin_amdgcn_mfma_f32_16x16x32_bf16(w1, rA1, aA, 0, 0, 0);
            f32x4 aB = __builtin_amdgcn_mfma_f32_16x16x32_bf16(w0, rB0, b, 0, 0, 0);
            aB = __builtin_amdgcn_mfma_f32_16x16x32_bf16(w1, rB1, aB, 0, 0, 0);
            pkA[nt] = sp_pk(aA);
            pkB[nt] = sp_pk(aB);
        }
        bf16x8 sA0 = as_bf16x8(gather8(pkA[0], pkA[1], idx0, idx1, hisel));
        bf16x8 sA1 = as_bf16x8(gather8(pkA[2], pkA[3], idx0, idx1, hisel));
        bf16x8 sB0 = as_bf16x8(gather8(pkB[0], pkB[1], idx0, idx1, hisel));
        bf16x8 sB1 = as_bf16x8(gather8(pkB[2], pkB[3], idx0, idx1, hisel));

        // ---- rgb layer 2: K=64, outs 0..2 (sigmoid) + epilogue ----
        {
            bf16x8 w0 = as_bf16x8(*(const u32x4a*)&sw[(34 * 64 + lane) * 8]);
            bf16x8 w1 = as_bf16x8(*(const u32x4a*)&sw[(35 * 64 + lane) * 8]);
            f32x4 b = *(const f32x4a*)&sb[208 + q4];
            f32x4 aA = __builtin_amdgcn_mfma_f32_16x16x32_bf16(w0, sA0, b, 0, 0, 0);
            aA = __builtin_amdgcn_mfma_f32_16x16x32_bf16(w1, sA1, aA, 0, 0, 0);
            f32x4 aB = __builtin_amdgcn_mfma_f32_16x16x32_bf16(w0, sB0, b, 0, 0, 0);
            aB = __builtin_amdgcn_mfma_f32_16x16x32_bf16(w1, sB1, aB, 0, 0, 0);
            if (q == 0) {  // lane c holds all channels of its points
                f32x4 oA;
                oA[0] = sigmoid_f(aA[0]);
                oA[1] = sigmoid_f(aA[1]);
                oA[2] = sigmoid_f(aA[2]);
                oA[3] = occA;
                *(f32x4a*)&out[(p0 + c) * 4] = oA;
                out[(long)4 * n + p0 + c] = occA;
                f32x4 oB;
                oB[0] = sigmoid_f(aB[0]);
                oB[1] = sigmoid_f(aB[1]);
                oB[2] = sigmoid_f(aB[2]);
                oB[3] = occB;
                *(f32x4a*)&out[(p0 + 16 + c) * 4] = oB;
                out[(long)4 * n + p0 + 16 + c] = occB;
            }
        }
    }
}

extern "C" void kernel_launch(void* const* d_in, const int* in_sizes, int n_in,
                              void* d_out, int out_size, void* d_ws, size_t ws_size,
                              hipStream_t stream) {
    const int n = in_sizes[0] / 32;  // N = 524288
    float*  wsf = (float*)d_ws;
    ushort* wsw = (ushort*)((char*)d_ws + 1152);
    prep_weights<<<8, 256, 0, stream>>>(
        (const float*)d_in[2], (const float*)d_in[3],
        (const float*)d_in[4], (const float*)d_in[5],
        (const float*)d_in[6], (const float*)d_in[7],
        (const float*)d_in[8], (const float*)d_in[9],
        (const float*)d_in[10], (const float*)d_in[11],
        (const float*)d_in[12], (const float*)d_in[13],
        (const float*)d_in[14], (const int*)d_in[15],
        wsf, wsw);
    net_mfma<<<n / 512, 512, 0, stream>>>(
        (const float*)d_in[0], (const float*)d_in[1],
        wsf, wsw, (float*)d_out, n);
}

// Round 9
// 213.452 us; speedup vs baseline: 1.1202x; 1.1202x over previous
//
#include <hip/hip_runtime.h>

typedef __bf16 bf16x8 __attribute__((ext_vector_type(8)));
typedef float f32x4 __attribute__((ext_vector_type(4)));
typedef unsigned int u32x4 __attribute__((ext_vector_type(4)));
typedef unsigned int u32x2 __attribute__((ext_vector_type(2)));
typedef u32x4 u32x4a __attribute__((may_alias));
typedef u32x2 u32x2a __attribute__((may_alias));
typedef f32x4 f32x4a __attribute__((may_alias));
typedef unsigned int u32a __attribute__((may_alias));

#define NITER 4  // 512-thread block => 8 waves * 32 pts * 4 = 1024 pts/block

__device__ inline unsigned short f2b(float f) {  // f32 -> bf16 RNE (prep only)
    unsigned int x;
    __builtin_memcpy(&x, &f, 4);
    unsigned int r = (x + 0x7FFFu + ((x >> 16) & 1u)) >> 16;
    return (unsigned short)r;
}
__device__ inline unsigned int cvt_pk_bf16(float lo, float hi) {
    unsigned int r;
    asm("v_cvt_pk_bf16_f32 %0, %1, %2" : "=v"(r) : "v"(lo), "v"(hi));
    return r;
}
__device__ inline float vexp2(float x) { float r; asm("v_exp_f32 %0, %1" : "=v"(r) : "v"(x)); return r; }
__device__ inline float vlog2(float x) { float r; asm("v_log_f32 %0, %1" : "=v"(r) : "v"(x)); return r; }
__device__ inline float vrcp(float x)  { float r; asm("v_rcp_f32 %0, %1" : "=v"(r) : "v"(x)); return r; }
// softplus(x) = ln2 * log2(1 + 2^(x*log2e)) — f32-safe for |x|<80
// NOTE: R6/R7 tried folding the log2e/ln2 constants into the weight table;
// both NaN'd on hardware (bisect: fold alone NaNs). Keep the 5-inst form.
__device__ inline float softplus_f(float x) {
    return 0.69314718f * vlog2(1.f + vexp2(1.44269504f * x));
}
__device__ inline float sigmoid_f(float x) {
    return vrcp(1.f + vexp2(-1.44269504f * x));
}
__device__ inline bf16x8 as_bf16x8(u32x4 v) { return __builtin_bit_cast(bf16x8, v); }

// softplus + pack to bf16x4 + b64 store
#define SPST(dstp, acc) { \
    u32x2 pk_ = {cvt_pk_bf16(softplus_f((acc)[0]), softplus_f((acc)[1])), \
                 cvt_pk_bf16(softplus_f((acc)[2]), softplus_f((acc)[3]))}; \
    *(u32x2a*)(dstp) = pk_; }

// ws layout: [0..287] f32 biases | byte 1152: ushort frag-major weights 36*64*8
// bias map: [0]ob0 [64]ob1 [128]ob2 [144]rb1 [208]rb2(pad->16) [224]rgb_b0'(folded latent)
// frag bases: occ0:0(Nt4,Kt1) occ1:4(4,2) occ2:12(1,2) rgb0:14(4,3) rgb1:26(4,2) rgb2:34(1,2)
// frag: lane l holds W[k=kt*32+(l>>4)*8+j][n=nt*16+(l&15)]
// rgb0 x-row map: k<32 emb, 32..58 dir(rows 32..58), 59..63 zero,
//                 64..95 feat tile: k-local kl=1..15 -> W row 58+kl, kl=0 & kl>=16 -> ZERO

__global__ __launch_bounds__(256) void prep_weights(
    const float* __restrict__ oW0, const float* __restrict__ ob0,
    const float* __restrict__ oW1, const float* __restrict__ ob1,
    const float* __restrict__ oW2, const float* __restrict__ ob2,
    const float* __restrict__ rW0, const float* __restrict__ rb0,
    const float* __restrict__ rW1, const float* __restrict__ rb1,
    const float* __restrict__ rW2, const float* __restrict__ rb2,
    const float* __restrict__ rlat, const int* __restrict__ lidx,
    float* __restrict__ wsf, ushort* __restrict__ wsw)
{
    const int bid = blockIdx.x, tid = threadIdx.x;
    __shared__ float red[256];

    if (bid == 0) {  // plain biases
        for (int i = tid; i < 224; i += 256) {
            float v;
            if (i < 64)       v = ob0[i];
            else if (i < 128) v = ob1[i - 64];
            else if (i < 144) v = ob2[i - 128];
            else if (i < 208) v = rb1[i - 144];
            else              v = (i - 208 < 3) ? rb2[i - 208] : 0.f;
            wsf[i] = v;
        }
    }
    if (bid == 7) {  // parallel latent fold: rgb_b0' = rgb_b0 + latent @ rgb_W0[74:202]
        const int outn = tid & 63, sl = tid >> 6;  // 4 slices x 32 k
        const float* lat = rlat + (size_t)lidx[0] * 128;
        float p = 0.f;
        for (int k = sl * 32; k < sl * 32 + 32; k++)
            p = fmaf(lat[k], rW0[(74 + k) * 64 + outn], p);
        red[tid] = p;
        __syncthreads();
        if (tid < 64)
            wsf[224 + tid] = rb0[tid] + red[tid] + red[64 + tid] + red[128 + tid] + red[192 + tid];
    }
    // fragment-major weight table: 2304 frag-lanes split across 8 blocks
    for (int t = tid; t < 288; t += 256) {
        const int s = bid * 288 + t;
        const int frag = s >> 6, lane = s & 63;
        const int qq = lane >> 4, cc = lane & 15;
        const float* W;
        int ldn = 64, nt = 0, kt = 0;
        bool isr0 = false, isr2 = false;
        if (frag < 4)       { W = oW0; nt = frag; kt = 0; }
        else if (frag < 12) { W = oW1; int f = frag - 4;  nt = f >> 1; kt = f & 1; }
        else if (frag < 14) { W = oW2; ldn = 16; nt = 0; kt = frag - 12; }
        else if (frag < 26) { W = rW0; int f = frag - 14; nt = f / 3; kt = f - nt * 3; isr0 = true; }
        else if (frag < 34) { W = rW1; int f = frag - 26; nt = f >> 1; kt = f & 1; }
        else                { W = rW2; ldn = 3; nt = 0; kt = frag - 34; isr2 = true; }
        const int nn = nt * 16 + cc;
        __align__(16) ushort vals[8];
#pragma unroll
        for (int j = 0; j < 8; j++) {
            int k = kt * 32 + qq * 8 + j;
            float v = 0.f;
            if (isr0) {
                int ks = -1;
                if (k < 59) ks = k;                            // emb + dir rows
                else if (k >= 65 && k < 80) ks = k - 65 + 59;  // feat kl=1..15 -> rows 59..73
                if (ks >= 0) v = W[ks * 64 + nn];
            } else if (isr2) {
                if (nn < 3) v = W[k * 3 + nn];
            } else {
                v = W[k * ldn + nn];
            }
            vals[j] = f2b(v);
        }
        *(u32x4a*)&wsw[s * 8] = *(const u32x4a*)vals;
    }
}

// Transposed-compute kernel: D = W^T_tile · X^T_tile (row=out, col=point).
// R8 = EXACT R4 (proven 69.5us, passed) + straight-line cross-iteration input
// prefetch ONLY (no lambda): iteration it's emb/dir f32 loads are issued during
// iteration it-1's layer compute, so the ~900cy HBM latency hides under the 6
// layers instead of stalling occ0. No numerics changed (R6/R7 folding NaN'd).
__global__ __launch_bounds__(512, 4) void net_mfma(
    const float* __restrict__ emb, const float* __restrict__ dir,
    const float* __restrict__ wsf, const ushort* __restrict__ wsw,
    float* __restrict__ out, int n)
{
    __shared__ __align__(16) ushort s_w[36 * 64 * 8];    // 36,864 B
    __shared__ __align__(16) ushort s_h[8][32 * 72];     // 36,864 B  activations, ld=72
    __shared__ __align__(16) float s_b[288];             //  1,152 B  biases (f32)

    const int tid = threadIdx.x;
    for (int i = tid; i < 36 * 64; i += 512)
        *(u32x4a*)&s_w[i * 8] = *(const u32x4a*)(wsw + i * 8);
    for (int i = tid; i < 288; i += 512) s_b[i] = wsf[i];
    __syncthreads();

    const int wave = tid >> 6, lane = tid & 63, q = lane >> 4, c = lane & 15;
    ushort* hw = s_h[wave];
    ushort* hA = hw + c * 72;          // group A point-row
    ushort* hB = hw + (c + 16) * 72;   // group B point-row
    // zero own activation slice once (garbage LDS could be NaN-patterned bf16)
    for (int i = lane; i < 1152; i += 64) ((u32a*)hw)[i] = 0u;

    const int q4 = q * 4, q8 = q * 8;
    const long dlim = (long)n * 27;

    // ---- cross-iteration prefetch state: 8 x f32x4 = 32 VGPR ----
    f32x4 peA0, peA1, peB0, peB1, pdA0, pdA1, pdB0, pdB1;
    // initial load (it = 0)
    {
        const long pp = (long)blockIdx.x * 1024 + wave * 32;
        const float* ep = emb + (pp + c) * 32 + q8;
        peA0 = *(const f32x4a*)ep;
        peA1 = *(const f32x4a*)(ep + 4);
        const float* ep2 = emb + (pp + 16 + c) * 32 + q8;
        peB0 = *(const f32x4a*)ep2;
        peB1 = *(const f32x4a*)(ep2 + 4);
        const long ibA = (pp + c) * 27 + q8;
        if (ibA + 8 <= dlim) {
            pdA0 = *(const f32x4a*)(dir + ibA);
            pdA1 = *(const f32x4a*)(dir + ibA + 4);
        } else {
#pragma unroll
            for (int j = 0; j < 4; j++) pdA0[j] = (ibA + j < dlim) ? dir[ibA + j] : 0.f;
#pragma unroll
            for (int j = 0; j < 4; j++) pdA1[j] = (ibA + 4 + j < dlim) ? dir[ibA + 4 + j] : 0.f;
        }
        const long ibB = (pp + 16 + c) * 27 + q8;
        if (ibB + 8 <= dlim) {
            pdB0 = *(const f32x4a*)(dir + ibB);
            pdB1 = *(const f32x4a*)(dir + ibB + 4);
        } else {
#pragma unroll
            for (int j = 0; j < 4; j++) pdB0[j] = (ibB + j < dlim) ? dir[ibB + j] : 0.f;
#pragma unroll
            for (int j = 0; j < 4; j++) pdB1[j] = (ibB + 4 + j < dlim) ? dir[ibB + 4 + j] : 0.f;
        }
    }

    for (int it = 0; it < NITER; ++it) {
        const ushort* sw = s_w;       // opaque per-iter bases: block LICM of the
        const float*  sb = s_b;       // weight-frag + bias LDS loads
        asm volatile("" : "+v"(sw), "+v"(sb));

        const long p0 = (long)blockIdx.x * 1024 + it * 256 + wave * 32;  // A: +c, B: +16+c

        // ---- convert current (prefetched) inputs to B-fragments ----
        bf16x8 x_embA, x_embB, x_dirA, x_dirB;
        {
            u32x4 pk = {cvt_pk_bf16(peA0[0], peA0[1]), cvt_pk_bf16(peA0[2], peA0[3]),
                        cvt_pk_bf16(peA1[0], peA1[1]), cvt_pk_bf16(peA1[2], peA1[3])};
            x_embA = as_bf16x8(pk);
            u32x4 pk2 = {cvt_pk_bf16(peB0[0], peB0[1]), cvt_pk_bf16(peB0[2], peB0[3]),
                         cvt_pk_bf16(peB1[0], peB1[1]), cvt_pk_bf16(peB1[2], peB1[3])};
            x_embB = as_bf16x8(pk2);
            // k-local >= 27 lanes carry garbage; rgb0 dir weight rows 27..31 are zero
            u32x4 pk3 = {cvt_pk_bf16(pdA0[0], pdA0[1]), cvt_pk_bf16(pdA0[2], pdA0[3]),
                         cvt_pk_bf16(pdA1[0], pdA1[1]), cvt_pk_bf16(pdA1[2], pdA1[3])};
            x_dirA = as_bf16x8(pk3);
            u32x4 pk4 = {cvt_pk_bf16(pdB0[0], pdB0[1]), cvt_pk_bf16(pdB0[2], pdB0[3]),
                         cvt_pk_bf16(pdB1[0], pdB1[1]), cvt_pk_bf16(pdB1[2], pdB1[3])};
            x_dirB = as_bf16x8(pk4);
        }
        // ---- issue next-iteration global loads now; they land under the 6 layers ----
        {
            const int itn = (it + 1 < NITER) ? it + 1 : it;  // last iter: benign reload
            const long pp = (long)blockIdx.x * 1024 + itn * 256 + wave * 32;
            const float* ep = emb + (pp + c) * 32 + q8;
            peA0 = *(const f32x4a*)ep;
            peA1 = *(const f32x4a*)(ep + 4);
            const float* ep2 = emb + (pp + 16 + c) * 32 + q8;
            peB0 = *(const f32x4a*)ep2;
            peB1 = *(const f32x4a*)(ep2 + 4);
            const long ibA = (pp + c) * 27 + q8;
            if (ibA + 8 <= dlim) {
                pdA0 = *(const f32x4a*)(dir + ibA);
                pdA1 = *(const f32x4a*)(dir + ibA + 4);
            } else {
#pragma unroll
                for (int j = 0; j < 4; j++) pdA0[j] = (ibA + j < dlim) ? dir[ibA + j] : 0.f;
#pragma unroll
                for (int j = 0; j < 4; j++) pdA1[j] = (ibA + 4 + j < dlim) ? dir[ibA + 4 + j] : 0.f;
            }
            const long ibB = (pp + 16 + c) * 27 + q8;
            if (ibB + 8 <= dlim) {
                pdB0 = *(const f32x4a*)(dir + ibB);
                pdB1 = *(const f32x4a*)(dir + ibB + 4);
            } else {
#pragma unroll
                for (int j = 0; j < 4; j++) pdB0[j] = (ibB + j < dlim) ? dir[ibB + j] : 0.f;
#pragma unroll
                for (int j = 0; j < 4; j++) pdB1[j] = (ibB + 4 + j < dlim) ? dir[ibB + 4 + j] : 0.f;
            }
        }

        // ---- occ layer 0: K=32 (emb), out 64 ----
#pragma unroll
        for (int nt = 0; nt < 4; ++nt) {
            bf16x8 w = as_bf16x8(*(const u32x4a*)&sw[((0 + nt) * 64 + lane) * 8]);
            f32x4 b = *(const f32x4a*)&sb[0 + nt * 16 + q4];
            f32x4 aA = __builtin_amdgcn_mfma_f32_16x16x32_bf16(w, x_embA, b, 0, 0, 0);
            f32x4 aB = __builtin_amdgcn_mfma_f32_16x16x32_bf16(w, x_embB, b, 0, 0, 0);
            SPST(&hA[nt * 16 + q4], aA);
            SPST(&hB[nt * 16 + q4], aB);
        }
        // ---- occ layer 1: K=64, out 64 ----
        {
            bf16x8 hA0 = as_bf16x8(*(const u32x4a*)&hA[0 + q8]);
            bf16x8 hA1 = as_bf16x8(*(const u32x4a*)&hA[32 + q8]);
            bf16x8 hB0 = as_bf16x8(*(const u32x4a*)&hB[0 + q8]);
            bf16x8 hB1 = as_bf16x8(*(const u32x4a*)&hB[32 + q8]);
#pragma unroll
            for (int nt = 0; nt < 4; ++nt) {
                bf16x8 w0 = as_bf16x8(*(const u32x4a*)&sw[((4 + nt * 2 + 0) * 64 + lane) * 8]);
                bf16x8 w1 = as_bf16x8(*(const u32x4a*)&sw[((4 + nt * 2 + 1) * 64 + lane) * 8]);
                f32x4 b = *(const f32x4a*)&sb[64 + nt * 16 + q4];
                f32x4 aA = __builtin_amdgcn_mfma_f32_16x16x32_bf16(w0, hA0, b, 0, 0, 0);
                aA = __builtin_amdgcn_mfma_f32_16x16x32_bf16(w1, hA1, aA, 0, 0, 0);
                f32x4 aB = __builtin_amdgcn_mfma_f32_16x16x32_bf16(w0, hB0, b, 0, 0, 0);
                aB = __builtin_amdgcn_mfma_f32_16x16x32_bf16(w1, hB1, aB, 0, 0, 0);
                SPST(&hA[nt * 16 + q4], aA);
                SPST(&hB[nt * 16 + q4], aB);
            }
        }
        // ---- occ layer 2: K=64, out 16 (raw -> feat k=0..15; occ = sigmoid(out0)) ----
        float occA, occB;
        {
            bf16x8 hA0 = as_bf16x8(*(const u32x4a*)&hA[0 + q8]);
            bf16x8 hA1 = as_bf16x8(*(const u32x4a*)&hA[32 + q8]);
            bf16x8 hB0 = as_bf16x8(*(const u32x4a*)&hB[0 + q8]);
            bf16x8 hB1 = as_bf16x8(*(const u32x4a*)&hB[32 + q8]);
            bf16x8 w0 = as_bf16x8(*(const u32x4a*)&sw[(12 * 64 + lane) * 8]);
            bf16x8 w1 = as_bf16x8(*(const u32x4a*)&sw[(13 * 64 + lane) * 8]);
            f32x4 b = *(const f32x4a*)&sb[128 + q4];
            f32x4 aA = __builtin_amdgcn_mfma_f32_16x16x32_bf16(w0, hA0, b, 0, 0, 0);
            aA = __builtin_amdgcn_mfma_f32_16x16x32_bf16(w1, hA1, aA, 0, 0, 0);
            f32x4 aB = __builtin_amdgcn_mfma_f32_16x16x32_bf16(w0, hB0, b, 0, 0, 0);
            aB = __builtin_amdgcn_mfma_f32_16x16x32_bf16(w1, hB1, aB, 0, 0, 0);
            occA = sigmoid_f(aA[0]);  // 1-exp(-softplus(h)) == sigmoid(h); valid on q==0
            occB = sigmoid_f(aB[0]);
            u32x2 pkA = {cvt_pk_bf16(aA[0], aA[1]), cvt_pk_bf16(aA[2], aA[3])};
            *(u32x2a*)&hA[q4] = pkA;  // raw outs 0..15 (out0 nulled by zero weight row)
            u32x2 pkB = {cvt_pk_bf16(aB[0], aB[1]), cvt_pk_bf16(aB[2], aB[3])};
            *(u32x2a*)&hB[q4] = pkB;
        }
        // ---- rgb layer 0: K=96 (emb|dir|feat), out 64, bias = folded rgb_b0' ----
        {
            // q>=2 reads stale h (k-local 16..31): finite garbage x zero weight rows
            bf16x8 xfA = as_bf16x8(*(const u32x4a*)&hA[q8]);
            bf16x8 xfB = as_bf16x8(*(const u32x4a*)&hB[q8]);
#pragma unroll
            for (int nt = 0; nt < 4; ++nt) {
                bf16x8 w0 = as_bf16x8(*(const u32x4a*)&sw[((14 + nt * 3 + 0) * 64 + lane) * 8]);
                bf16x8 w1 = as_bf16x8(*(const u32x4a*)&sw[((14 + nt * 3 + 1) * 64 + lane) * 8]);
                bf16x8 w2 = as_bf16x8(*(const u32x4a*)&sw[((14 + nt * 3 + 2) * 64 + lane) * 8]);
                f32x4 b = *(const f32x4a*)&sb[224 + nt * 16 + q4];
                f32x4 aA = __builtin_amdgcn_mfma_f32_16x16x32_bf16(w0, x_embA, b, 0, 0, 0);
                aA = __builtin_amdgcn_mfma_f32_16x16x32_bf16(w1, x_dirA, aA, 0, 0, 0);
                aA = __builtin_amdgcn_mfma_f32_16x16x32_bf16(w2, xfA, aA, 0, 0, 0);
                f32x4 aB = __builtin_amdgcn_mfma_f32_16x16x32_bf16(w0, x_embB, b, 0, 0, 0);
                aB = __builtin_amdgcn_mfma_f32_16x16x32_bf16(w1, x_dirB, aB, 0, 0, 0);
                aB = __builtin_amdgcn_mfma_f32_16x16x32_bf16(w2, xfB, aB, 0, 0, 0);
                SPST(&hA[nt * 16 + q4], aA);
                SPST(&hB[nt * 16 + q4], aB);
            }
        }
        // ---- rgb layer 1: K=64, out 64 ----
        {
            bf16x8 hA0 = as_bf16x8(*(const u32x4a*)&hA[0 + q8]);
            bf16x8 hA1 = as_bf16x8(*(const u32x4a*)&hA[32 + q8]);
            bf16x8 hB0 = as_bf16x8(*(const u32x4a*)&hB[0 + q8]);
            bf16x8 hB1 = as_bf16x8(*(const u32x4a*)&hB[32 + q8]);
#pragma unroll
            for (int nt = 0; nt < 4; ++nt) {
                bf16x8 w0 = as_bf16x8(*(const u32x4a*)&sw[((26 + nt * 2 + 0) * 64 + lane) * 8]);
                bf16x8 w1 = as_bf16x8(*(const u32x4a*)&sw[((26 + nt * 2 + 1) * 64 + lane) * 8]);
                f32x4 b = *(const f32x4a*)&sb[144 + nt * 16 + q4];
                f32x4 aA = __builtin_amdgcn_mfma_f32_16x16x32_bf16(w0, hA0, b, 0, 0, 0);
                aA = __builtin_amdgcn_mfma_f32_16x16x32_bf16(w1, hA1, aA, 0, 0, 0);
                f32x4 aB = __builtin_amdgcn_mfma_f32_16x16x32_bf16(w0, hB0, b, 0, 0, 0);
                aB = __builtin_amdgcn_mfma_f32_16x16x32_bf16(w1, hB1, aB, 0, 0, 0);
                SPST(&hA[nt * 16 + q4], aA);
                SPST(&hB[nt * 16 + q4], aB);
            }
        }
        // ---- rgb layer 2: K=64, outs 0..2 (sigmoid) + epilogue ----
        {
            bf16x8 hA0 = as_bf16x8(*(const u32x4a*)&hA[0 + q8]);
            bf16x8 hA1 = as_bf16x8(*(const u32x4a*)&hA[32 + q8]);
            bf16x8 hB0 = as_bf16x8(*(const u32x4a*)&hB[0 + q8]);
            bf16x8 hB1 = as_bf16x8(*(const u32x4a*)&hB[32 + q8]);
            bf16x8 w0 = as_bf16x8(*(const u32x4a*)&sw[(34 * 64 + lane) * 8]);
            bf16x8 w1 = as_bf16x8(*(const u32x4a*)&sw[(35 * 64 + lane) * 8]);
            f32x4 b = *(const f32x4a*)&sb[208 + q4];
            f32x4 aA = __builtin_amdgcn_mfma_f32_16x16x32_bf16(w0, hA0, b, 0, 0, 0);
            aA = __builtin_amdgcn_mfma_f32_16x16x32_bf16(w1, hA1, aA, 0, 0, 0);
            f32x4 aB = __builtin_amdgcn_mfma_f32_16x16x32_bf16(w0, hB0, b, 0, 0, 0);
            aB = __builtin_amdgcn_mfma_f32_16x16x32_bf16(w1, hB1, aB, 0, 0, 0);
            if (q == 0) {  // lane c holds all channels of its points
                f32x4 oA;
                oA[0] = sigmoid_f(aA[0]);
                oA[1] = sigmoid_f(aA[1]);
                oA[2] = sigmoid_f(aA[2]);
                oA[3] = occA;
                *(f32x4a*)&out[(p0 + c) * 4] = oA;
                out[(long)4 * n + p0 + c] = occA;
                f32x4 oB;
                oB[0] = sigmoid_f(aB[0]);
                oB[1] = sigmoid_f(aB[1]);
                oB[2] = sigmoid_f(aB[2]);
                oB[3] = occB;
                *(f32x4a*)&out[(p0 + 16 + c) * 4] = oB;
                out[(long)4 * n + p0 + 16 + c] = occB;
            }
        }
    }
}

extern "C" void kernel_launch(void* const* d_in, const int* in_sizes, int n_in,
                              void* d_out, int out_size, void* d_ws, size_t ws_size,
                              hipStream_t stream) {
    const int n = in_sizes[0] / 32;  // N = 524288
    float*  wsf = (float*)d_ws;
    ushort* wsw = (ushort*)((char*)d_ws + 1152);
    prep_weights<<<8, 256, 0, stream>>>(
        (const float*)d_in[2], (const float*)d_in[3],
        (const float*)d_in[4], (const float*)d_in[5],
        (const float*)d_in[6], (const float*)d_in[7],
        (const float*)d_in[8], (const float*)d_in[9],
        (const float*)d_in[10], (const float*)d_in[11],
        (const float*)d_in[12], (const float*)d_in[13],
        (const float*)d_in[14], (const int*)d_in[15],
        wsf, wsw);
    net_mfma<<<n / 1024, 512, 0, stream>>>(
        (const float*)d_in[0], (const float*)d_in[1],
        wsf, wsw, (float*)d_out, n);
}